// Round 8
// baseline (1303.735 us; speedup 1.0000x reference)
//
#include <hip/hip_runtime.h>
#include <hip/hip_cooperative_groups.h>
#include <hip/hip_bf16.h>
#include <stdint.h>

namespace cg = cooperative_groups;

__device__ inline int imin(int a, int b) { return a < b ? a : b; }
__device__ inline int imax(int a, int b) { return a > b ? a : b; }
__device__ inline float bf2f(unsigned short u) {
    return __uint_as_float(((unsigned int)u) << 16);
}
__device__ inline unsigned short f2bf(float v) {
    unsigned int u = __float_as_uint(v);
    unsigned int r = u + 0x7FFFu + ((u >> 16) & 1u);
    return (unsigned short)(r >> 16);
}

typedef __attribute__((ext_vector_type(8))) short short8;   // 8 bf16 = 4 VGPRs
typedef __attribute__((ext_vector_type(4))) float floatx4;  // MFMA C/D

// ================= shared device-function phase bodies =================

__device__ inline void prologue_elem(size_t i, int n, int* __restrict__ cnt,
                                     const float* __restrict__ x, unsigned short* __restrict__ xb, size_t nx,
                                     const float* __restrict__ W1, unsigned short* __restrict__ W1T,
                                     const float* __restrict__ W2, unsigned short* __restrict__ W2T,
                                     const float* __restrict__ W3, unsigned short* __restrict__ W3T) {
    if (i < (size_t)n) { cnt[i] = 0; return; }
    size_t j = i - n;
    if (j < nx) { xb[j] = f2bf(x[j]); return; }
    size_t k = j - nx;
    const int n1 = 128 * 256, n2 = 256 * 128, n3 = 128 * 64;
    if (k < (size_t)(n1 + n2 + n3)) {
        int idx = (int)k;
        if (idx < n1) {
            int kk = idx >> 8, nn = idx & 255;            // W1: K=128, Nc=256
            W1T[nn * 128 + kk] = f2bf(W1[idx]);
        } else if (idx < n1 + n2) {
            int jj = idx - n1;
            int kk = jj >> 7, nn = jj & 127;              // W2: K=256, Nc=128
            W2T[nn * 256 + kk] = f2bf(W2[jj]);
        } else {
            int jj = idx - n1 - n2;
            int kk = jj >> 6, nn = jj & 63;               // W3: K=128, Nc=64
            W3T[nn * 128 + kk] = f2bf(W3[jj]);
        }
    }
}

__device__ inline void scan1_chunk(int chunk, int tid, int* __restrict__ tmp,
                                   const int* __restrict__ cnt,
                                   int* __restrict__ partial, int* __restrict__ bsum, int n) {
    int i = chunk * 256 + tid;
    int v = (i < n) ? ((cnt[i] + 3) & ~3) : 0;
    tmp[tid] = v;
    __syncthreads();
    #pragma unroll
    for (int s = 1; s < 256; s <<= 1) {
        int t = (tid >= s) ? tmp[tid - s] : 0;
        __syncthreads();
        tmp[tid] += t;
        __syncthreads();
    }
    if (i < n) partial[i] = tmp[tid] - v;
    if (tid == 255) bsum[chunk] = tmp[255];
}

__device__ inline void scan2_block(int tid, int* __restrict__ tmp, int* __restrict__ carry,
                                   const int* __restrict__ bsum, int* __restrict__ bsumoff, int nb) {
    if (tid == 0) *carry = 0;
    __syncthreads();
    for (int base = 0; base < nb; base += 256) {
        int i = base + tid;
        int v = (i < nb) ? bsum[i] : 0;
        tmp[tid] = v;
        __syncthreads();
        #pragma unroll
        for (int s = 1; s < 256; s <<= 1) {
            int t = (tid >= s) ? tmp[tid - s] : 0;
            __syncthreads();
            tmp[tid] += t;
            __syncthreads();
        }
        if (i < nb) bsumoff[i] = *carry + tmp[tid] - v;
        __syncthreads();
        if (tid == 0) *carry += tmp[255];
        __syncthreads();
    }
}

template <bool USEW>
__device__ inline void scan3_elem(int i, int boff,
                                  const int* __restrict__ partial, const int* __restrict__ cnt,
                                  int* __restrict__ offs, float* __restrict__ dinv,
                                  unsigned long long* __restrict__ edges, int* __restrict__ csr_src,
                                  int n) {
    int v = partial[i] + boff;
    int c = imax(cnt[i], 0);
    offs[i] = v;
    if (i == n - 1) offs[n] = v + ((c + 3) & ~3);
    float d = (float)c + 1.0f;
    dinv[i] = rsqrtf(d);
    int end = v + ((c + 3) & ~3);
    for (int p = v + c; p < end; p++) {
        if (USEW) edges[p] = 0ull;
        else csr_src[p] = 0;
    }
}

template <bool USEW>
__device__ inline void fill_elem(int e, const int* __restrict__ row, const int* __restrict__ col,
                                 const int* __restrict__ offs, const int* __restrict__ rank,
                                 const float* __restrict__ dinv,
                                 unsigned long long* __restrict__ edges, int* __restrict__ csr_src,
                                 int n, int cap) {
    int c = imax(0, imin(col[e], n - 1));
    int r = imax(0, imin(row[e], n - 1));
    int pos = offs[c] + rank[e];
    pos = imax(0, imin(pos, cap - 1));
    if (USEW) {
        unsigned long long rec = (unsigned long long)(unsigned)r
                               | ((unsigned long long)__float_as_uint(dinv[r]) << 32);
        edges[pos] = rec;
    } else {
        csr_src[pos] = r;
    }
}

// ---- MFMA GEMM tile (device body; caller supplies LDS + tile coords) ----

template <int NT, int FOUT, bool EPI>
__device__ void gemm_tile(const unsigned short* __restrict__ act,
                          const unsigned short* __restrict__ WT,
                          unsigned short* __restrict__ H,
                          const float* __restrict__ bias,
                          int nrows, int Fin, int bx, int by, int tid,
                          unsigned short* __restrict__ sA, unsigned short* __restrict__ sB) {
    constexpr int CT = NT / 16;
    const int w = tid >> 6;
    const int lane = tid & 63;
    const int quad = lane >> 4;
    const int l15 = lane & 15;
    const int row0 = bx * 128;
    const int col0 = by * NT;

    floatx4 acc[2][CT] = {};

    const int sr = tid >> 1;
    const int sp = (tid & 1) * 16;

    for (int k0 = 0; k0 < Fin; k0 += 32) {
        __syncthreads();
        {
            int grow = row0 + sr;
            uint4 v0 = make_uint4(0, 0, 0, 0), v1 = make_uint4(0, 0, 0, 0);
            if (grow < nrows) {
                const uint4* ap = (const uint4*)&act[(size_t)grow * Fin + k0 + sp];
                v0 = ap[0]; v1 = ap[1];
            }
            uint4* dst = (uint4*)&sA[sr * 40 + sp];
            dst[0] = v0; dst[1] = v1;
        }
        if (NT == 128 || tid < 128) {
            const uint4* wp = (const uint4*)&WT[(size_t)(col0 + sr) * Fin + k0 + sp];
            uint4* dst = (uint4*)&sB[sr * 40 + sp];
            dst[0] = wp[0]; dst[1] = wp[1];
        }
        __syncthreads();

        short8 bfr[CT];
        #pragma unroll
        for (int ct = 0; ct < CT; ct++)
            bfr[ct] = *(const short8*)&sB[(ct * 16 + l15) * 40 + quad * 8];
        #pragma unroll
        for (int rt = 0; rt < 2; rt++) {
            short8 afr = *(const short8*)&sA[(w * 32 + rt * 16 + l15) * 40 + quad * 8];
            #pragma unroll
            for (int ct = 0; ct < CT; ct++)
                acc[rt][ct] = __builtin_amdgcn_mfma_f32_16x16x32_bf16(afr, bfr[ct], acc[rt][ct], 0, 0, 0);
        }
    }

    #pragma unroll
    for (int rt = 0; rt < 2; rt++) {
        #pragma unroll
        for (int ct = 0; ct < CT; ct++) {
            int gcol = col0 + ct * 16 + l15;
            #pragma unroll
            for (int r = 0; r < 4; r++) {
                int grow = row0 + w * 32 + rt * 16 + quad * 4 + r;
                if (grow < nrows) {
                    float v = acc[rt][ct][r];
                    if (EPI) v = fmaxf(v + bias[gcol], 0.f);
                    H[(size_t)grow * FOUT + gcol] = f2bf(v);
                }
            }
        }
    }
}

// ---- small 64->32 GEMM tile ----

__device__ void gemm32_tile(const unsigned short* __restrict__ act,
                            const float* __restrict__ W,
                            unsigned short* __restrict__ H,
                            int nrows, int bx, int tid,
                            float* __restrict__ sA, float* __restrict__ sW) {
    const int row0 = bx * 32;
    const int Fin = 64, strA = 68;

    __syncthreads();   // protect LDS reuse across tiles / phases

    for (int i = tid; i < 32 * Fin; i += 256) {
        int r = i >> 6;
        int k = i & 63;
        float v = 0.f;
        if (row0 + r < nrows) v = bf2f(act[(size_t)row0 * Fin + i]);
        sA[r * strA + k] = v;
        (void)k;
    }

    const int rl = tid >> 3;
    const int cg_ = tid & 7;
    float a0 = 0.f, a1 = 0.f, a2 = 0.f, a3 = 0.f;

    for (int k0 = 0; k0 < Fin; k0 += 16) {
        __syncthreads();
        const float* wsrc = W + (size_t)k0 * 32;
        for (int i = tid; i < 16 * 32; i += 256) sW[i] = wsrc[i];
        __syncthreads();
        #pragma unroll 4
        for (int kk = 0; kk < 16; kk++) {
            float a = sA[rl * strA + k0 + kk];
            float4 wv = *(const float4*)&sW[kk * 32 + cg_ * 4];
            a0 = fmaf(a, wv.x, a0);
            a1 = fmaf(a, wv.y, a1);
            a2 = fmaf(a, wv.z, a2);
            a3 = fmaf(a, wv.w, a3);
        }
    }

    const int rowi = row0 + rl;
    if (rowi < nrows) {
        unsigned short* hp = &H[(size_t)rowi * 32 + cg_ * 4];
        hp[0] = f2bf(a0); hp[1] = f2bf(a1); hp[2] = f2bf(a2); hp[3] = f2bf(a3);
    }
}

__device__ inline void heads_one(int idx, const unsigned short* __restrict__ act,
                                 const float* __restrict__ Wmu, const float* __restrict__ Wls,
                                 unsigned short* __restrict__ H) {
    int r = idx >> 5;
    int c = idx & 31;
    const float* Wp = (c < 16) ? Wmu : Wls;
    int cc = c & 15;
    float acc = 0.f;
    #pragma unroll 8
    for (int k = 0; k < 32; k++)
        acc = fmaf(bf2f(act[(size_t)r * 32 + k]), Wp[k * 16 + cc], acc);
    H[idx] = f2bf(acc);
}

// ---- aggregation body: 8B/lane gathers (ushort4), 16-deep main + 4-wide tail ----

template <int F, bool RELU, bool HASBIAS, bool USEW>
__device__ inline void agg_one(int node, int ln,
                               const unsigned short* __restrict__ Hb,
                               unsigned short* __restrict__ out,
                               const int* __restrict__ offs,
                               const unsigned long long* __restrict__ edges,
                               const int* __restrict__ src,
                               const float* __restrict__ dinv,
                               const float* __restrict__ bias,
                               int Ecap) {
    int f0 = 4 * ln;

    float di = dinv[node];
    ushort4 sv = *(const ushort4*)&Hb[(size_t)node * F + f0];
    float acc0 = di * bf2f(sv.x);
    float acc1 = di * bf2f(sv.y);
    float acc2 = di * bf2f(sv.z);
    float acc3 = di * bf2f(sv.w);

    int s0 = offs[node];
    int s1 = offs[node + 1];
    s0 = imax(0, imin(s0, Ecap));
    s1 = imax(s0, imin(s1, Ecap));
    int e = s0;
    for (; e + 16 <= s1; e += 16) {
        int sr[16];
        float wv[16];
        if (USEW) {
            #pragma unroll
            for (int q = 0; q < 8; q++) {
                uint4 pr = *(const uint4*)(edges + e + 2 * q);
                sr[2 * q] = (int)pr.x;     wv[2 * q] = __uint_as_float(pr.y);
                sr[2 * q + 1] = (int)pr.z; wv[2 * q + 1] = __uint_as_float(pr.w);
            }
        } else {
            #pragma unroll
            for (int q = 0; q < 4; q++) {
                int4 a = *(const int4*)(src + e + 4 * q);
                sr[4 * q] = a.x; sr[4 * q + 1] = a.y; sr[4 * q + 2] = a.z; sr[4 * q + 3] = a.w;
            }
            #pragma unroll
            for (int q = 0; q < 16; q++) wv[q] = dinv[sr[q]];
        }
        ushort4 h[16];
        #pragma unroll
        for (int q = 0; q < 16; q++)
            h[q] = *(const ushort4*)&Hb[(size_t)sr[q] * F + f0];
        #pragma unroll
        for (int q = 0; q < 16; q++) {
            acc0 = fmaf(wv[q], bf2f(h[q].x), acc0);
            acc1 = fmaf(wv[q], bf2f(h[q].y), acc1);
            acc2 = fmaf(wv[q], bf2f(h[q].z), acc2);
            acc3 = fmaf(wv[q], bf2f(h[q].w), acc3);
        }
    }
    for (; e < s1; e += 4) {
        int sr[4];
        float wv[4];
        if (USEW) {
            uint4 p0 = *(const uint4*)(edges + e);
            uint4 p1 = *(const uint4*)(edges + e + 2);
            sr[0] = (int)p0.x; wv[0] = __uint_as_float(p0.y);
            sr[1] = (int)p0.z; wv[1] = __uint_as_float(p0.w);
            sr[2] = (int)p1.x; wv[2] = __uint_as_float(p1.y);
            sr[3] = (int)p1.z; wv[3] = __uint_as_float(p1.w);
        } else {
            int4 a = *(const int4*)(src + e);
            sr[0] = a.x; sr[1] = a.y; sr[2] = a.z; sr[3] = a.w;
            #pragma unroll
            for (int q = 0; q < 4; q++) wv[q] = dinv[sr[q]];
        }
        ushort4 h[4];
        #pragma unroll
        for (int q = 0; q < 4; q++)
            h[q] = *(const ushort4*)&Hb[(size_t)sr[q] * F + f0];
        #pragma unroll
        for (int q = 0; q < 4; q++) {
            acc0 = fmaf(wv[q], bf2f(h[q].x), acc0);
            acc1 = fmaf(wv[q], bf2f(h[q].y), acc1);
            acc2 = fmaf(wv[q], bf2f(h[q].z), acc2);
            acc3 = fmaf(wv[q], bf2f(h[q].w), acc3);
        }
    }
    float v0 = di * acc0;
    float v1 = di * acc1;
    float v2 = di * acc2;
    float v3 = di * acc3;
    if (HASBIAS) { v0 += bias[f0]; v1 += bias[f0 + 1]; v2 += bias[f0 + 2]; v3 += bias[f0 + 3]; }
    if (RELU) {
        v0 = fmaxf(v0, 0.f); v1 = fmaxf(v1, 0.f);
        v2 = fmaxf(v2, 0.f); v3 = fmaxf(v3, 0.f);
    }
    ushort4 o;
    o.x = f2bf(v0); o.y = f2bf(v1); o.z = f2bf(v2); o.w = f2bf(v3);
    *(ushort4*)&out[(size_t)node * F + f0] = o;
}

template <bool USEW>
__device__ inline void agg_heads_one(int node, int ln,
                                     const unsigned short* __restrict__ Hb,
                                     float* __restrict__ out,
                                     const int* __restrict__ offs,
                                     const unsigned long long* __restrict__ edges,
                                     const int* __restrict__ src,
                                     const float* __restrict__ dinv,
                                     const float* __restrict__ bmu, const float* __restrict__ bls,
                                     int nnodes, int Ecap) {
    constexpr int F = 32;
    int f0 = 4 * ln;

    float di = dinv[node];
    ushort4 sv = *(const ushort4*)&Hb[(size_t)node * F + f0];
    float acc0 = di * bf2f(sv.x);
    float acc1 = di * bf2f(sv.y);
    float acc2 = di * bf2f(sv.z);
    float acc3 = di * bf2f(sv.w);

    int s0 = offs[node];
    int s1 = offs[node + 1];
    s0 = imax(0, imin(s0, Ecap));
    s1 = imax(s0, imin(s1, Ecap));
    int e = s0;
    for (; e + 16 <= s1; e += 16) {
        int sr[16];
        float wv[16];
        if (USEW) {
            #pragma unroll
            for (int q = 0; q < 8; q++) {
                uint4 pr = *(const uint4*)(edges + e + 2 * q);
                sr[2 * q] = (int)pr.x;     wv[2 * q] = __uint_as_float(pr.y);
                sr[2 * q + 1] = (int)pr.z; wv[2 * q + 1] = __uint_as_float(pr.w);
            }
        } else {
            #pragma unroll
            for (int q = 0; q < 4; q++) {
                int4 a = *(const int4*)(src + e + 4 * q);
                sr[4 * q] = a.x; sr[4 * q + 1] = a.y; sr[4 * q + 2] = a.z; sr[4 * q + 3] = a.w;
            }
            #pragma unroll
            for (int q = 0; q < 16; q++) wv[q] = dinv[sr[q]];
        }
        ushort4 h[16];
        #pragma unroll
        for (int q = 0; q < 16; q++)
            h[q] = *(const ushort4*)&Hb[(size_t)sr[q] * F + f0];
        #pragma unroll
        for (int q = 0; q < 16; q++) {
            acc0 = fmaf(wv[q], bf2f(h[q].x), acc0);
            acc1 = fmaf(wv[q], bf2f(h[q].y), acc1);
            acc2 = fmaf(wv[q], bf2f(h[q].z), acc2);
            acc3 = fmaf(wv[q], bf2f(h[q].w), acc3);
        }
    }
    for (; e < s1; e += 4) {
        int sr[4];
        float wv[4];
        if (USEW) {
            uint4 p0 = *(const uint4*)(edges + e);
            uint4 p1 = *(const uint4*)(edges + e + 2);
            sr[0] = (int)p0.x; wv[0] = __uint_as_float(p0.y);
            sr[1] = (int)p0.z; wv[1] = __uint_as_float(p0.w);
            sr[2] = (int)p1.x; wv[2] = __uint_as_float(p1.y);
            sr[3] = (int)p1.z; wv[3] = __uint_as_float(p1.w);
        } else {
            int4 a = *(const int4*)(src + e);
            sr[0] = a.x; sr[1] = a.y; sr[2] = a.z; sr[3] = a.w;
            #pragma unroll
            for (int q = 0; q < 4; q++) wv[q] = dinv[sr[q]];
        }
        ushort4 h[4];
        #pragma unroll
        for (int q = 0; q < 4; q++)
            h[q] = *(const ushort4*)&Hb[(size_t)sr[q] * F + f0];
        #pragma unroll
        for (int q = 0; q < 4; q++) {
            acc0 = fmaf(wv[q], bf2f(h[q].x), acc0);
            acc1 = fmaf(wv[q], bf2f(h[q].y), acc1);
            acc2 = fmaf(wv[q], bf2f(h[q].z), acc2);
            acc3 = fmaf(wv[q], bf2f(h[q].w), acc3);
        }
    }
    const float* bp = (f0 < 16) ? bmu : bls;
    int fb = f0 & 15;
    float v0 = fmaf(di, acc0, bp[fb]);
    float v1 = fmaf(di, acc1, bp[fb + 1]);
    float v2 = fmaf(di, acc2, bp[fb + 2]);
    float v3 = fmaf(di, acc3, bp[fb + 3]);
    float* op = (f0 < 16) ? (out + (size_t)node * 16 + fb)
                          : (out + (size_t)nnodes * 16 + (size_t)node * 16 + fb);
    *(float4*)op = make_float4(v0, v1, v2, v3);
}

// ================= fused cooperative mega-kernel =================

struct MegaP {
    const float* x;
    const int* row; const int* col;
    const float *W1, *b1, *W2, *b2, *W3, *b3, *W4, *b4, *Wmu, *bmu, *Wls, *bls;
    unsigned short *act, *H, *xb, *xa, *W1T, *W2T, *W3T;
    float* dinv;
    int *cnt, *offs, *partial, *bsum, *bsumoff, *rank;
    unsigned long long* edges;
    int* csr_src;
    float* outF;
    int N, E, nb, E8;
};

template <int F, bool RELU, bool HASBIAS, bool USEW>
__device__ inline void agg_phase(long long g0, long long T,
                                 const unsigned short* Hb, unsigned short* out,
                                 const float* bias, const MegaP& P) {
    constexpr int TPN = F / 4;
    long long total = (long long)P.N * TPN;
    for (long long t = g0; t < total; t += T) {
        int node = (int)(t / TPN);
        int ln = (int)(t % TPN);
        agg_one<F, RELU, HASBIAS, USEW>(node, ln, Hb, out, P.offs, P.edges, P.csr_src,
                                        P.dinv, bias, P.E8);
    }
}

template <bool USEW>
__global__ __launch_bounds__(256, 2) void k_mega(MegaP P) {
    cg::grid_group grid = cg::this_grid();
    __shared__ __align__(16) unsigned char SMEM[20480];
    const int tid = threadIdx.x;
    const int G = gridDim.x;
    const long long T = (long long)G * 256;
    const long long g0 = (long long)blockIdx.x * 256 + tid;

    // P0: zero cnt + x->bf16 + weight transposes
    {
        size_t total = (size_t)P.N + (size_t)P.N * 128 + (128 * 256 + 256 * 128 + 128 * 64);
        for (size_t i = (size_t)g0; i < total; i += (size_t)T)
            prologue_elem(i, P.N, P.cnt, P.x, P.xb, (size_t)P.N * 128,
                          P.W1, P.W1T, P.W2, P.W2T, P.W3, P.W3T);
    }
    grid.sync();
    // P1: degree count + rank
    for (long long e = g0; e < P.E; e += T) {
        int c = imax(0, imin(P.col[e], P.N - 1));
        P.rank[e] = atomicAdd(&P.cnt[c], 1);
    }
    grid.sync();
    // P2: per-chunk scan
    {
        int* tmp = (int*)SMEM;
        for (int chunk = blockIdx.x; chunk < P.nb; chunk += G) {
            __syncthreads();
            scan1_chunk(chunk, tid, tmp, P.cnt, P.partial, P.bsum, P.N);
        }
    }
    grid.sync();
    // P3: block-sum scan (single block)
    if (blockIdx.x == 0) {
        int* tmp = (int*)SMEM;
        int* carry = (int*)(SMEM + 1024);
        scan2_block(tid, tmp, carry, P.bsum, P.bsumoff, P.nb);
    }
    grid.sync();
    // P4: offsets + dinv + pad slots
    for (long long i = g0; i < P.N; i += T)
        scan3_elem<USEW>((int)i, P.bsumoff[i >> 8], P.partial, P.cnt,
                         P.offs, P.dinv, P.edges, P.csr_src, P.N);
    grid.sync();
    // P5: CSR fill
    for (long long e = g0; e < P.E; e += T)
        fill_elem<USEW>((int)e, P.row, P.col, P.offs, P.rank, P.dinv,
                        P.edges, P.csr_src, P.N, P.E8);
    grid.sync();
    // P6: layer-1 aggregation on x (F=128)
    agg_phase<128, false, false, USEW>(g0, T, P.xb, P.xa, nullptr, P);
    grid.sync();
    // P7: GEMM1 xa@W1 -> act (relu+bias), FOUT=256
    {
        unsigned short* sA = (unsigned short*)SMEM;
        unsigned short* sB = sA + 128 * 40;
        int gx = (P.N + 127) >> 7;
        for (int tile = blockIdx.x; tile < gx * 2; tile += G)
            gemm_tile<128, 256, true>(P.xa, P.W1T, P.act, P.b1, P.N, 128,
                                      tile % gx, tile / gx, tid, sA, sB);
    }
    grid.sync();
    // P8: GEMM2 act@W2 -> H (F=128)
    {
        unsigned short* sA = (unsigned short*)SMEM;
        unsigned short* sB = sA + 128 * 40;
        int gx = (P.N + 127) >> 7;
        for (int tile = blockIdx.x; tile < gx; tile += G)
            gemm_tile<128, 128, false>(P.act, P.W2T, P.H, nullptr, P.N, 256,
                                       tile, 0, tid, sA, sB);
    }
    grid.sync();
    // P9: layer-2 aggregation (F=128, relu, b2)
    agg_phase<128, true, true, USEW>(g0, T, P.H, P.act, P.b2, P);
    grid.sync();
    // P10: GEMM3 act@W3 -> H (F=64)
    {
        unsigned short* sA = (unsigned short*)SMEM;
        unsigned short* sB = sA + 128 * 40;
        int gx = (P.N + 127) >> 7;
        for (int tile = blockIdx.x; tile < gx; tile += G)
            gemm_tile<64, 64, false>(P.act, P.W3T, P.H, nullptr, P.N, 128,
                                     tile, 0, tid, sA, sB);
    }
    grid.sync();
    // P11: layer-3 aggregation (F=64, relu, b3)
    agg_phase<64, true, true, USEW>(g0, T, P.H, P.act, P.b3, P);
    grid.sync();
    // P12: GEMM4 act@W4 -> H (F=32)
    {
        float* sA32 = (float*)SMEM;
        float* sW = (float*)(SMEM + 32 * 68 * 4);
        int nt = (P.N + 31) >> 5;
        for (int tile = blockIdx.x; tile < nt; tile += G)
            gemm32_tile(P.act, P.W4, P.H, P.N, tile, tid, sA32, sW);
    }
    grid.sync();
    // P13: layer-4 aggregation (F=32, relu, b4)
    agg_phase<32, true, true, USEW>(g0, T, P.H, P.act, P.b4, P);
    grid.sync();
    // P14: heads GEMM act -> H (mu|ls, F=32)
    for (long long idx = g0; idx < (long long)P.N * 32; idx += T)
        heads_one((int)idx, P.act, P.Wmu, P.Wls, P.H);
    grid.sync();
    // P15: heads aggregation -> out
    {
        constexpr int TPN = 8;
        long long total = (long long)P.N * TPN;
        for (long long t = g0; t < total; t += T) {
            int node = (int)(t / TPN);
            int ln = (int)(t % TPN);
            agg_heads_one<USEW>(node, ln, P.H, P.outF, P.offs, P.edges, P.csr_src,
                                P.dinv, P.bmu, P.bls, P.N, P.E8);
        }
    }
}

// ================= fallback multi-kernel path (wrappers) =================

__global__ void k_prologue(int* cnt, int n, const float* x, unsigned short* xb, size_t nx,
                           const float* W1, unsigned short* W1T,
                           const float* W2, unsigned short* W2T,
                           const float* W3, unsigned short* W3T) {
    size_t i = (size_t)blockIdx.x * 256 + threadIdx.x;
    size_t total = (size_t)n + nx + (128 * 256 + 256 * 128 + 128 * 64);
    if (i < total) prologue_elem(i, n, cnt, x, xb, nx, W1, W1T, W2, W2T, W3, W3T);
}

__global__ void k_count(const int* col, int* cnt, int* rank, int E, int n) {
    int e = blockIdx.x * blockDim.x + threadIdx.x;
    if (e < E) {
        int c = imax(0, imin(col[e], n - 1));
        rank[e] = atomicAdd(&cnt[c], 1);
    }
}

__global__ __launch_bounds__(256) void k_scan1(const int* cnt, int* partial, int* bsum, int n) {
    __shared__ int tmp[256];
    scan1_chunk(blockIdx.x, threadIdx.x, tmp, cnt, partial, bsum, n);
}

__global__ __launch_bounds__(256) void k_scan2(const int* bsum, int* bsumoff, int nb) {
    __shared__ int tmp[256];
    __shared__ int carry;
    scan2_block(threadIdx.x, tmp, &carry, bsum, bsumoff, nb);
}

template <bool USEW>
__global__ __launch_bounds__(256) void k_scan3(const int* partial, const int* bsumoff,
                                               const int* cnt, int* offs, float* dinv,
                                               unsigned long long* edges, int* csr_src, int n) {
    int i = blockIdx.x * 256 + threadIdx.x;
    if (i < n)
        scan3_elem<USEW>(i, bsumoff[blockIdx.x], partial, cnt, offs, dinv, edges, csr_src, n);
}

template <bool USEW>
__global__ void k_fill(const int* row, const int* col, const int* offs, const int* rank,
                       const float* dinv, unsigned long long* edges, int* csr_src,
                       int E, int n, int cap) {
    int e = blockIdx.x * blockDim.x + threadIdx.x;
    if (e < E) fill_elem<USEW>(e, row, col, offs, rank, dinv, edges, csr_src, n, cap);
}

template <int NT, int FOUT, bool EPI>
__global__ __launch_bounds__(256) void k_gemm_mfma(const unsigned short* act,
                                                   const unsigned short* WT,
                                                   unsigned short* H, const float* bias,
                                                   int nrows, int Fin) {
    __shared__ __align__(16) unsigned short sA[128 * 40];
    __shared__ __align__(16) unsigned short sB[NT * 40];
    gemm_tile<NT, FOUT, EPI>(act, WT, H, bias, nrows, Fin, blockIdx.x, blockIdx.y,
                             threadIdx.x, sA, sB);
}

__global__ __launch_bounds__(256) void k_gemm32(const unsigned short* act, const float* W,
                                                unsigned short* H, int nrows) {
    __shared__ __align__(16) float sA[32 * 68];
    __shared__ __align__(16) float sW[16 * 32];
    gemm32_tile(act, W, H, nrows, blockIdx.x, threadIdx.x, sA, sW);
}

__global__ void k_gemm_heads(const unsigned short* act, const float* Wmu, const float* Wls,
                             unsigned short* H, int nrows) {
    int idx = blockIdx.x * blockDim.x + threadIdx.x;
    if (idx < nrows * 32) heads_one(idx, act, Wmu, Wls, H);
}

template <int F, bool RELU, bool HASBIAS, bool USEW>
__global__ __launch_bounds__(256) void k_aggb(const unsigned short* Hb, unsigned short* out,
                                              const int* offs, const unsigned long long* edges,
                                              const int* src, const float* dinv,
                                              const float* bias, int nnodes, int Ecap) {
    constexpr int TPN = F / 4;
    int t = blockIdx.x * 256 + threadIdx.x;
    int node = t / TPN;
    int ln = t % TPN;
    if (node < nnodes)
        agg_one<F, RELU, HASBIAS, USEW>(node, ln, Hb, out, offs, edges, src, dinv, bias, Ecap);
}

template <bool USEW>
__global__ __launch_bounds__(256) void k_agg_heads(const unsigned short* Hb, float* out,
                                                   const int* offs, const unsigned long long* edges,
                                                   const int* src, const float* dinv,
                                                   const float* bmu, const float* bls,
                                                   int nnodes, int Ecap) {
    constexpr int TPN = 8;
    int t = blockIdx.x * 256 + threadIdx.x;
    int node = t / TPN;
    int ln = t % TPN;
    if (node < nnodes)
        agg_heads_one<USEW>(node, ln, Hb, out, offs, edges, src, dinv, bmu, bls, nnodes, Ecap);
}

// ================= host pipeline =================

struct WsLayout {
    unsigned short *act, *H, *xb, *xa, *W1T, *W2T, *W3T;
    float* dinv;
    int *cnt, *offs, *partial, *bsum, *bsumoff, *rank;
    unsigned long long* edges;
    int* csr_src;
};

static WsLayout layout_ws(void* d_ws, int N, int E, bool usew) {
    auto align16 = [](char* p) { return (char*)(((uintptr_t)p + 15) & ~(uintptr_t)15); };
    const int nb = (N + 255) / 256;
    WsLayout L;
    char* p = (char*)d_ws;
    L.act = (unsigned short*)p;   p += (size_t)N * 256 * 2;
    L.H = (unsigned short*)p;     p += (size_t)N * 256 * 2;
    L.xb = L.H;                   // alias (dead before H first write)
    L.xa = (unsigned short*)p;    p += (size_t)N * 128 * 2;
    L.dinv = (float*)p;           p += (size_t)N * 4;
    L.cnt = (int*)p;              p += (size_t)N * 4;
    L.offs = (int*)p;             p += (size_t)(N + 1) * 4;
    L.partial = (int*)p;          p += (size_t)N * 4;
    L.bsum = (int*)p;             p += (size_t)nb * 4;
    L.bsumoff = (int*)p;          p += (size_t)nb * 4;
    p = align16(p);
    L.rank = (int*)p;             p += (size_t)E * 4;
    p = align16(p);
    L.W1T = (unsigned short*)p;   p += 256 * 128 * 2;
    L.W2T = (unsigned short*)p;   p += 128 * 256 * 2;
    L.W3T = (unsigned short*)p;   p += 64 * 128 * 2;
    p = align16(p);
    L.edges = usew ? (unsigned long long*)p : nullptr;
    L.csr_src = usew ? nullptr : (int*)p;
    return L;
}

template <bool USEW>
static void run_pipeline(void* const* d_in, void* d_out, void* d_ws,
                         int N, int E, hipStream_t stream) {
    const float* x  = (const float*)d_in[0];
    const int* ei   = (const int*)d_in[1];
    const float* W1 = (const float*)d_in[2];
    const float* b1 = (const float*)d_in[3];
    const float* W2 = (const float*)d_in[4];
    const float* b2 = (const float*)d_in[5];
    const float* W3 = (const float*)d_in[6];
    const float* b3 = (const float*)d_in[7];
    const float* W4 = (const float*)d_in[8];
    const float* b4 = (const float*)d_in[9];
    const float* Wmu = (const float*)d_in[10];
    const float* bmu = (const float*)d_in[11];
    const float* Wls = (const float*)d_in[12];
    const float* bls = (const float*)d_in[13];
    const int* row = ei;
    const int* col = ei + E;
    const int nb = (N + 255) / 256;
    const int E8 = E + 8 * N;

    WsLayout L = layout_ws(d_ws, N, E, USEW);

    {
        size_t total = (size_t)N + (size_t)N * 128 + (128 * 256 + 256 * 128 + 128 * 64);
        k_prologue<<<(unsigned)((total + 255) / 256), 256, 0, stream>>>(
            L.cnt, N, x, L.xb, (size_t)N * 128, W1, L.W1T, W2, L.W2T, W3, L.W3T);
    }
    k_count<<<(E + 255) / 256, 256, 0, stream>>>(col, L.cnt, L.rank, E, N);
    k_scan1<<<nb, 256, 0, stream>>>(L.cnt, L.partial, L.bsum, N);
    k_scan2<<<1, 256, 0, stream>>>(L.bsum, L.bsumoff, nb);
    k_scan3<USEW><<<nb, 256, 0, stream>>>(L.partial, L.bsumoff, L.cnt, L.offs, L.dinv, L.edges, L.csr_src, N);
    k_fill<USEW><<<(E + 255) / 256, 256, 0, stream>>>(row, col, L.offs, L.rank, L.dinv, L.edges, L.csr_src, E, N, E8);

    const int gx = (N + 127) / 128;
    k_aggb<128, false, false, USEW><<<(unsigned)(((size_t)N * 32 + 255) / 256), 256, 0, stream>>>(L.xb, L.xa, L.offs, L.edges, L.csr_src, L.dinv, nullptr, N, E8);
    k_gemm_mfma<128, 256, true><<<dim3(gx, 2), 256, 0, stream>>>(L.xa, L.W1T, L.act, b1, N, 128);
    k_gemm_mfma<128, 128, false><<<dim3(gx, 1), 256, 0, stream>>>(L.act, L.W2T, L.H, nullptr, N, 256);
    k_aggb<128, true, true, USEW><<<(unsigned)(((size_t)N * 32 + 255) / 256), 256, 0, stream>>>(L.H, L.act, L.offs, L.edges, L.csr_src, L.dinv, b2, N, E8);
    k_gemm_mfma<64, 64, false><<<dim3(gx, 1), 256, 0, stream>>>(L.act, L.W3T, L.H, nullptr, N, 128);
    k_aggb<64, true, true, USEW><<<(unsigned)(((size_t)N * 16 + 255) / 256), 256, 0, stream>>>(L.H, L.act, L.offs, L.edges, L.csr_src, L.dinv, b3, N, E8);
    k_gemm32<<<(N + 31) / 32, 256, 0, stream>>>(L.act, W4, L.H, N);
    k_aggb<32, true, true, USEW><<<(unsigned)(((size_t)N * 8 + 255) / 256), 256, 0, stream>>>(L.H, L.act, L.offs, L.edges, L.csr_src, L.dinv, b4, N, E8);
    float* outF = (float*)d_out;
    k_gemm_heads<<<(unsigned)(((size_t)N * 32 + 255) / 256), 256, 0, stream>>>(L.act, Wmu, Wls, L.H, N);
    k_agg_heads<USEW><<<(unsigned)(((size_t)N * 8 + 255) / 256), 256, 0, stream>>>(L.H, outF, L.offs, L.edges, L.csr_src, L.dinv, bmu, bls, N, E8);
}

extern "C" void kernel_launch(void* const* d_in, const int* in_sizes, int n_in,
                              void* d_out, int out_size, void* d_ws, size_t ws_size,
                              hipStream_t stream) {
    const int N = in_sizes[0] / 128;
    const int E = in_sizes[1] / 2;
    const int nb = (N + 255) / 256;
    const size_t E8cap = (size_t)E + 8 * (size_t)N;

    size_t fixed = (size_t)N * 256 * 2 * 2 + (size_t)N * 128 * 2
                 + (size_t)N * 4 * 4 + 4 + (size_t)nb * 8 + (size_t)E * 4
                 + (256 * 128 + 128 * 256 + 64 * 128) * 2 + 128;
    size_t need_w = fixed + E8cap * 8;
    bool usew = (ws_size >= need_w);

    WsLayout L = layout_ws(d_ws, N, E, usew);

    MegaP P;
    P.x = (const float*)d_in[0];
    P.row = (const int*)d_in[1];
    P.col = (const int*)d_in[1] + E;
    P.W1 = (const float*)d_in[2];  P.b1 = (const float*)d_in[3];
    P.W2 = (const float*)d_in[4];  P.b2 = (const float*)d_in[5];
    P.W3 = (const float*)d_in[6];  P.b3 = (const float*)d_in[7];
    P.W4 = (const float*)d_in[8];  P.b4 = (const float*)d_in[9];
    P.Wmu = (const float*)d_in[10]; P.bmu = (const float*)d_in[11];
    P.Wls = (const float*)d_in[12]; P.bls = (const float*)d_in[13];
    P.act = L.act; P.H = L.H; P.xb = L.xb; P.xa = L.xa;
    P.W1T = L.W1T; P.W2T = L.W2T; P.W3T = L.W3T;
    P.dinv = L.dinv; P.cnt = L.cnt; P.offs = L.offs; P.partial = L.partial;
    P.bsum = L.bsum; P.bsumoff = L.bsumoff; P.rank = L.rank;
    P.edges = L.edges; P.csr_src = L.csr_src;
    P.outF = (float*)d_out;
    P.N = N; P.E = E; P.nb = nb; P.E8 = E + 8 * N;

    void* kargs[] = { (void*)&P };
    hipError_t err;
    if (usew)
        err = hipLaunchCooperativeKernel((const void*)k_mega<true>, dim3(512), dim3(256),
                                         kargs, 0, stream);
    else
        err = hipLaunchCooperativeKernel((const void*)k_mega<false>, dim3(512), dim3(256),
                                         kargs, 0, stream);
    if (err != hipSuccess) {
        // fallback: proven multi-kernel path
        if (usew) run_pipeline<true>(d_in, d_out, d_ws, N, E, stream);
        else      run_pipeline<false>(d_in, d_out, d_ws, N, E, stream);
    }
}